// Round 1
// baseline (110.334 us; speedup 1.0000x reference)
//
#include <hip/hip_runtime.h>
#include <hip/hip_bf16.h>
#include <stdint.h>

// BatchHardTripletLoss: N=4096, D=512, C=128, margin=0.3
// dist monotone-decreasing in gram => hardest-pos = min gram (same label, j!=i),
// hardest-neg = max gram (diff label). Gram never materialized: fused tile epilogue
// + order-preserving-uint atomics into per-row arrays.

#define NROW 4096
#define DIM  512
#define NCLS 128
#define MARGIN 0.3f
#define BT 128
#define BK 32

typedef __attribute__((ext_vector_type(8))) __bf16 bf16x8;
typedef __attribute__((ext_vector_type(4))) float  f32x4;

// monotone float<->uint: order-preserving for atomicMin/Max on unsigned
__device__ __forceinline__ unsigned enc(float f) {
    unsigned u = __float_as_uint(f);
    return (u & 0x80000000u) ? ~u : (u | 0x80000000u);
}
__device__ __forceinline__ float dec(unsigned e) {
    return (e & 0x80000000u) ? __uint_as_float(e & 0x7fffffffu)
                             : __uint_as_float(~e);
}

__device__ __forceinline__ unsigned short f2bf(float f) {
    __hip_bfloat16 h = __float2bfloat16(f);
    return *reinterpret_cast<unsigned short*>(&h);
}

__device__ __forceinline__ void async_copy16(const void* g, void* l) {
    __builtin_amdgcn_global_load_lds(
        (const __attribute__((address_space(1))) unsigned int*)g,
        (__attribute__((address_space(3))) unsigned int*)l,
        16, 0, 0);
}

// ---- kernel 1: init reduction arrays + class histogram bins ----
__global__ void tl_init(unsigned* __restrict__ posArr, unsigned* __restrict__ negArr,
                        int* __restrict__ cnt) {
    int t = blockIdx.x * blockDim.x + threadIdx.x;
    if (t < NROW) { posArr[t] = 0xFFFFFFFFu; negArr[t] = 0u; }
    if (t < NCLS) cnt[t] = 0;
}

// ---- kernel 2: L2-normalize rows -> bf16, plus class histogram ----
// one wave per row; 4 waves/block
__global__ void tl_norm(const float* __restrict__ E, const int* __restrict__ labels,
                        __hip_bfloat16* __restrict__ Ebf, int* __restrict__ cnt) {
    int wave = threadIdx.x >> 6;
    int lane = threadIdx.x & 63;
    int row  = blockIdx.x * 4 + wave;

    const float4* src = (const float4*)(E + (size_t)row * DIM); // 128 float4/row
    float4 v0 = src[lane];
    float4 v1 = src[lane + 64];
    float ss = v0.x*v0.x + v0.y*v0.y + v0.z*v0.z + v0.w*v0.w
             + v1.x*v1.x + v1.y*v1.y + v1.z*v1.z + v1.w*v1.w;
    #pragma unroll
    for (int m = 32; m >= 1; m >>= 1) ss += __shfl_xor(ss, m);
    float inv = 1.0f / fmaxf(sqrtf(ss), 1e-12f);

    ushort4 o0, o1;
    o0.x = f2bf(v0.x * inv); o0.y = f2bf(v0.y * inv);
    o0.z = f2bf(v0.z * inv); o0.w = f2bf(v0.w * inv);
    o1.x = f2bf(v1.x * inv); o1.y = f2bf(v1.y * inv);
    o1.z = f2bf(v1.z * inv); o1.w = f2bf(v1.w * inv);
    ushort4* dst = (ushort4*)(Ebf + (size_t)row * DIM);
    dst[lane]      = o0;
    dst[lane + 64] = o1;

    if (lane == 0) atomicAdd(&cnt[labels[row]], 1);
}

// ---- kernel 3: tiled bf16 MFMA Gram with fused masked min/max epilogue ----
// 128x128 tile per block, 4 waves in 2x2, each wave 4x4 of 16x16x32 MFMA.
__global__ void tl_gram(const __hip_bfloat16* __restrict__ Ebf,
                        const int* __restrict__ labels,
                        unsigned* __restrict__ posArr,
                        unsigned* __restrict__ negArr) {
    __shared__ __align__(16) __hip_bfloat16 At[BT * BK]; // [row][k], 8 KB
    __shared__ __align__(16) __hip_bfloat16 Bt[BT * BK]; // [col][k], 8 KB
    __shared__ int rowLab[BT];
    __shared__ int colLab[BT];

    const int tid  = threadIdx.x;
    const int wave = tid >> 6;
    const int lane = tid & 63;
    const int quad = lane >> 4;
    const int l16  = lane & 15;
    const int wr   = wave >> 1;   // wave row (0..1): rows wr*64..+63
    const int wc   = wave & 1;    // wave col (0..1): cols wc*64..+63
    const int tileI = blockIdx.y * BT;
    const int tileJ = blockIdx.x * BT;

    if (tid < BT) rowLab[tid] = labels[tileI + tid];
    else          colLab[tid - BT] = labels[tileJ + (tid - BT)];

    // staging geometry: chunk c = wave*2+t covers LDS rows [c*16, c*16+16),
    // lane l -> LDS base + l*16 B -> row c*16 + l/4, k = (l&3)*8
    const int sRow = wave * 32 + (lane >> 2);
    const int sK   = (lane & 3) * 8;
    const __hip_bfloat16* gA = Ebf + (size_t)(tileI + sRow) * DIM + sK;
    const __hip_bfloat16* gB = Ebf + (size_t)(tileJ + sRow) * DIM + sK;
    __hip_bfloat16* lA0 = &At[(wave * 2 + 0) * 512]; // wave-uniform LDS base
    __hip_bfloat16* lA1 = &At[(wave * 2 + 1) * 512];
    __hip_bfloat16* lB0 = &Bt[(wave * 2 + 0) * 512];
    __hip_bfloat16* lB1 = &Bt[(wave * 2 + 1) * 512];

    f32x4 acc[4][4] = {};

    for (int k0 = 0; k0 < DIM; k0 += BK) {
        async_copy16(gA + k0,            lA0);
        async_copy16(gA + k0 + 16 * DIM, lA1);
        async_copy16(gB + k0,            lB0);
        async_copy16(gB + k0 + 16 * DIM, lB1);
        __syncthreads();  // drains vmcnt (global_load_lds) + lgkm

        bf16x8 a[4], b[4];
        #pragma unroll
        for (int mi = 0; mi < 4; mi++)
            a[mi] = *(const bf16x8*)&At[(wr * 64 + mi * 16 + l16) * BK + quad * 8];
        #pragma unroll
        for (int ni = 0; ni < 4; ni++)
            b[ni] = *(const bf16x8*)&Bt[(wc * 64 + ni * 16 + l16) * BK + quad * 8];

        #pragma unroll
        for (int mi = 0; mi < 4; mi++)
            #pragma unroll
            for (int ni = 0; ni < 4; ni++)
                acc[mi][ni] = __builtin_amdgcn_mfma_f32_16x16x32_bf16(
                    a[mi], b[ni], acc[mi][ni], 0, 0, 0);

        __syncthreads();  // single-buffered LDS: protect next staging
    }

    // epilogue: C/D layout col=lane&15, row=quad*4+reg (verified m89/m91)
    #pragma unroll
    for (int mi = 0; mi < 4; mi++) {
        #pragma unroll
        for (int reg = 0; reg < 4; reg++) {
            const int rloc = wr * 64 + mi * 16 + quad * 4 + reg;
            const int lr   = rowLab[rloc];
            const int gi   = tileI + rloc;
            float pmin =  INFINITY;   // min gram over positives (j != i)
            float nmax = -INFINITY;   // max gram over negatives
            #pragma unroll
            for (int ni = 0; ni < 4; ni++) {
                const int cloc = wc * 64 + ni * 16 + l16;
                const int gj   = tileJ + cloc;
                const float g  = acc[mi][ni][reg];
                const bool same = (lr == colLab[cloc]);
                if (same && gi != gj) pmin = fminf(pmin, g);
                if (!same)            nmax = fmaxf(nmax, g);
            }
            // fold across the quad's 16 lanes (covers wave's 64 cols)
            #pragma unroll
            for (int m = 1; m < 16; m <<= 1) {
                pmin = fminf(pmin, __shfl_xor(pmin, m));
                nmax = fmaxf(nmax, __shfl_xor(nmax, m));
            }
            if (l16 == 0) {
                if (pmin <  INFINITY) atomicMin(&posArr[gi], enc(pmin));
                if (nmax > -INFINITY) atomicMax(&negArr[gi], enc(nmax));
            }
        }
    }
}

// ---- kernel 4: per-row loss + mean over valid rows ----
__global__ void tl_final(const unsigned* __restrict__ posArr,
                         const unsigned* __restrict__ negArr,
                         const int* __restrict__ labels,
                         const int* __restrict__ cnt,
                         float* __restrict__ out) {
    const int tid = threadIdx.x; // 256 threads
    float sum = 0.0f;
    int   count = 0;
    for (int i = tid; i < NROW; i += 256) {
        const int c = cnt[labels[i]];
        const bool valid = (c >= 2) && (c < NROW); // has positive & has negative
        const float gp = dec(posArr[i]);
        const float gn = dec(negArr[i]);
        const float dap = sqrtf(fmaxf(2.0f - 2.0f * gp, 0.0f));
        const float dan = sqrtf(fmaxf(2.0f - 2.0f * gn, 0.0f));
        const float per = fmaxf(dap - dan + MARGIN, 0.0f);
        if (valid) { sum += per; count += 1; }
    }
    #pragma unroll
    for (int m = 32; m >= 1; m >>= 1) {
        sum   += __shfl_xor(sum, m);
        count += __shfl_xor(count, m);
    }
    __shared__ float ssum[4];
    __shared__ int   scnt[4];
    const int wave = tid >> 6, lane = tid & 63;
    if (lane == 0) { ssum[wave] = sum; scnt[wave] = count; }
    __syncthreads();
    if (tid == 0) {
        float s = ssum[0] + ssum[1] + ssum[2] + ssum[3];
        int   c = scnt[0] + scnt[1] + scnt[2] + scnt[3];
        out[0] = (c > 0) ? (s / (float)c) : 0.0f;
    }
}

extern "C" void kernel_launch(void* const* d_in, const int* in_sizes, int n_in,
                              void* d_out, int out_size, void* d_ws, size_t ws_size,
                              hipStream_t stream) {
    const float* E      = (const float*)d_in[0];
    const int*   labels = (const int*)d_in[1];
    float*       out    = (float*)d_out;

    char* ws = (char*)d_ws;
    __hip_bfloat16* Ebf   = (__hip_bfloat16*)ws;                       // 4 MB
    unsigned* posArr      = (unsigned*)(ws + (size_t)NROW * DIM * 2);  // 16 KB
    unsigned* negArr      = posArr + NROW;                             // 16 KB
    int* cnt              = (int*)(negArr + NROW);                     // 512 B

    tl_init<<<NROW / 256, 256, 0, stream>>>(posArr, negArr, cnt);
    tl_norm<<<NROW / 4, 256, 0, stream>>>(E, labels, Ebf, cnt);
    dim3 grid(NROW / BT, NROW / BT);
    tl_gram<<<grid, 256, 0, stream>>>(Ebf, labels, posArr, negArr);
    tl_final<<<1, 256, 0, stream>>>(posArr, negArr, labels, cnt, out);
}

// Round 2
// 93.433 us; speedup vs baseline: 1.1809x; 1.1809x over previous
//
#include <hip/hip_runtime.h>
#include <hip/hip_bf16.h>
#include <stdint.h>

// BatchHardTripletLoss: N=4096, D=512, C=128, margin=0.3
// dist monotone-decreasing in gram => hardest-pos = min gram (same label, j!=i),
// hardest-neg = max gram (diff label). Gram is symmetric => compute only upper
// triangular tiles (528 of 1024); each off-diag tile feeds both row- and
// col-direction reductions. Validity from reduction sentinels (no histogram).

#define NROW 4096
#define DIM  512
#define MARGIN 0.3f
#define BT 128
#define BK 32
#define NTILE (NROW / BT)                 // 32
#define NPAIR (NTILE * (NTILE + 1) / 2)   // 528
#define POS_INIT 0xFFFFFFFFu
#define NEG_INIT 0u

typedef __attribute__((ext_vector_type(8))) __bf16 bf16x8;
typedef __attribute__((ext_vector_type(4))) float  f32x4;

// monotone float<->uint: order-preserving for atomicMin/Max on unsigned.
// enc(finite f) can never equal POS_INIT (needs NaN) nor NEG_INIT (needs -NaN),
// so the init sentinels double as "no positive/negative seen" flags.
__device__ __forceinline__ unsigned enc(float f) {
    unsigned u = __float_as_uint(f);
    return (u & 0x80000000u) ? ~u : (u | 0x80000000u);
}
__device__ __forceinline__ float dec(unsigned e) {
    return (e & 0x80000000u) ? __uint_as_float(e & 0x7fffffffu)
                             : __uint_as_float(~e);
}

__device__ __forceinline__ unsigned short f2bf(float f) {
    __hip_bfloat16 h = __float2bfloat16(f);
    return *reinterpret_cast<unsigned short*>(&h);
}

__device__ __forceinline__ void async_copy16(const void* g, void* l) {
    __builtin_amdgcn_global_load_lds(
        (const __attribute__((address_space(1))) unsigned int*)g,
        (__attribute__((address_space(3))) unsigned int*)l,
        16, 0, 0);
}

// ---- kernel 1: L2-normalize rows -> bf16, + init reduction arrays ----
// one wave per row; 4 waves/block; 1024 blocks (first 16 also init pos/neg)
__global__ void tl_norm(const float* __restrict__ E,
                        __hip_bfloat16* __restrict__ Ebf,
                        unsigned* __restrict__ posArr,
                        unsigned* __restrict__ negArr) {
    if (blockIdx.x < 16) {
        int t = blockIdx.x * 256 + threadIdx.x;   // covers 4096
        posArr[t] = POS_INIT;
        negArr[t] = NEG_INIT;
    }
    int wave = threadIdx.x >> 6;
    int lane = threadIdx.x & 63;
    int row  = blockIdx.x * 4 + wave;

    const float4* src = (const float4*)(E + (size_t)row * DIM); // 128 float4/row
    float4 v0 = src[lane];
    float4 v1 = src[lane + 64];
    float ss = v0.x*v0.x + v0.y*v0.y + v0.z*v0.z + v0.w*v0.w
             + v1.x*v1.x + v1.y*v1.y + v1.z*v1.z + v1.w*v1.w;
    #pragma unroll
    for (int m = 32; m >= 1; m >>= 1) ss += __shfl_xor(ss, m);
    float inv = 1.0f / fmaxf(sqrtf(ss), 1e-12f);

    ushort4 o0, o1;
    o0.x = f2bf(v0.x * inv); o0.y = f2bf(v0.y * inv);
    o0.z = f2bf(v0.z * inv); o0.w = f2bf(v0.w * inv);
    o1.x = f2bf(v1.x * inv); o1.y = f2bf(v1.y * inv);
    o1.z = f2bf(v1.z * inv); o1.w = f2bf(v1.w * inv);
    ushort4* dst = (ushort4*)(Ebf + (size_t)row * DIM);
    dst[lane]      = o0;
    dst[lane + 64] = o1;
}

// ---- kernel 2: upper-triangular tiled bf16 MFMA Gram, fused min/max ----
// 128x128 tile per block, 4 waves in 2x2, each wave 4x4 of 16x16x32 MFMA.
__global__ void tl_gram(const __hip_bfloat16* __restrict__ Ebf,
                        const int* __restrict__ labels,
                        unsigned* __restrict__ posArr,
                        unsigned* __restrict__ negArr) {
    __shared__ __align__(16) __hip_bfloat16 At[BT * BK]; // [row][k], 8 KB
    __shared__ __align__(16) __hip_bfloat16 Bt[BT * BK]; // [col][k], 8 KB
    __shared__ int rowLab[BT];
    __shared__ int colLab[BT];

    // triangular decode: blockIdx.x -> (bi, bj) with bi <= bj
    int t = blockIdx.x, bi = 0, rowlen = NTILE;
    while (t >= rowlen) { t -= rowlen; rowlen--; bi++; }
    const int bj = bi + t;

    const int tid  = threadIdx.x;
    const int wave = tid >> 6;
    const int lane = tid & 63;
    const int quad = lane >> 4;
    const int l16  = lane & 15;
    const int wr   = wave >> 1;   // wave row (0..1): rows wr*64..+63
    const int wc   = wave & 1;    // wave col (0..1): cols wc*64..+63
    const int tileI = bi * BT;
    const int tileJ = bj * BT;
    const bool diag = (bi == bj);

    if (tid < BT) rowLab[tid] = labels[tileI + tid];
    else          colLab[tid - BT] = labels[tileJ + (tid - BT)];

    // staging: chunk c = wave*2+t covers LDS rows [c*16, c*16+16);
    // lane l -> base + l*16 B -> row c*16 + l/4, k = (l&3)*8 (wave-uniform base)
    const int sRow = wave * 32 + (lane >> 2);
    const int sK   = (lane & 3) * 8;
    const __hip_bfloat16* gA = Ebf + (size_t)(tileI + sRow) * DIM + sK;
    const __hip_bfloat16* gB = Ebf + (size_t)(tileJ + sRow) * DIM + sK;
    __hip_bfloat16* lA0 = &At[(wave * 2 + 0) * 512];
    __hip_bfloat16* lA1 = &At[(wave * 2 + 1) * 512];
    __hip_bfloat16* lB0 = &Bt[(wave * 2 + 0) * 512];
    __hip_bfloat16* lB1 = &Bt[(wave * 2 + 1) * 512];

    f32x4 acc[4][4] = {};

    for (int k0 = 0; k0 < DIM; k0 += BK) {
        async_copy16(gA + k0,            lA0);
        async_copy16(gA + k0 + 16 * DIM, lA1);
        async_copy16(gB + k0,            lB0);
        async_copy16(gB + k0 + 16 * DIM, lB1);
        __syncthreads();

        bf16x8 a[4], b[4];
        #pragma unroll
        for (int mi = 0; mi < 4; mi++)
            a[mi] = *(const bf16x8*)&At[(wr * 64 + mi * 16 + l16) * BK + quad * 8];
        #pragma unroll
        for (int ni = 0; ni < 4; ni++)
            b[ni] = *(const bf16x8*)&Bt[(wc * 64 + ni * 16 + l16) * BK + quad * 8];

        #pragma unroll
        for (int mi = 0; mi < 4; mi++)
            #pragma unroll
            for (int ni = 0; ni < 4; ni++)
                acc[mi][ni] = __builtin_amdgcn_mfma_f32_16x16x32_bf16(
                    a[mi], b[ni], acc[mi][ni], 0, 0, 0);

        __syncthreads();
    }

    // C/D layout: col = wc*64+ni*16+l16 (lane), row = wr*64+mi*16+quad*4+reg
    // Preload this lane's 16 row labels and 4 col labels from LDS.
    int rl[16], cl[4], clocv[4];
    #pragma unroll
    for (int mi = 0; mi < 4; mi++)
        #pragma unroll
        for (int reg = 0; reg < 4; reg++)
            rl[mi * 4 + reg] = rowLab[wr * 64 + mi * 16 + quad * 4 + reg];
    #pragma unroll
    for (int ni = 0; ni < 4; ni++) {
        clocv[ni] = wc * 64 + ni * 16 + l16;
        cl[ni] = colLab[clocv[ni]];
    }

    // ---- row pass: reduce over this tile's columns, for rows of tileI ----
    #pragma unroll
    for (int mi = 0; mi < 4; mi++) {
        #pragma unroll
        for (int reg = 0; reg < 4; reg++) {
            const int rloc = wr * 64 + mi * 16 + quad * 4 + reg;
            const int lr   = rl[mi * 4 + reg];
            const int gi   = tileI + rloc;
            float pmin =  INFINITY;
            float nmax = -INFINITY;
            #pragma unroll
            for (int ni = 0; ni < 4; ni++) {
                const int gj  = tileJ + clocv[ni];
                const float g = acc[mi][ni][reg];
                const bool same = (lr == cl[ni]);
                if (same && gi != gj) pmin = fminf(pmin, g);
                if (!same)            nmax = fmaxf(nmax, g);
            }
            #pragma unroll
            for (int m = 1; m < 16; m <<= 1) {
                pmin = fminf(pmin, __shfl_xor(pmin, m));
                nmax = fmaxf(nmax, __shfl_xor(nmax, m));
            }
            if (l16 == 0) {
                if (pmin <  INFINITY) atomicMin(&posArr[gi], enc(pmin));
                if (nmax > -INFINITY) atomicMax(&negArr[gi], enc(nmax));
            }
        }
    }

    // ---- col pass (off-diag only): reduce over rows, for rows of tileJ ----
    // gram(i,j)==gram(j,i); no self-pairs since bi != bj.
    if (!diag) {
        #pragma unroll
        for (int ni = 0; ni < 4; ni++) {
            const int lc = cl[ni];
            const int gj = tileJ + clocv[ni];
            float pmin =  INFINITY;
            float nmax = -INFINITY;
            #pragma unroll
            for (int mi = 0; mi < 4; mi++) {
                #pragma unroll
                for (int reg = 0; reg < 4; reg++) {
                    const float g = acc[mi][ni][reg];
                    const bool same = (rl[mi * 4 + reg] == lc);
                    if (same) pmin = fminf(pmin, g);
                    else      nmax = fmaxf(nmax, g);
                }
            }
            // fold across the 4 quads (same l16): lanes l16, +16, +32, +48
            pmin = fminf(pmin, __shfl_xor(pmin, 16));
            pmin = fminf(pmin, __shfl_xor(pmin, 32));
            nmax = fmaxf(nmax, __shfl_xor(nmax, 16));
            nmax = fmaxf(nmax, __shfl_xor(nmax, 32));
            if (quad == 0) {
                if (pmin <  INFINITY) atomicMin(&posArr[gj], enc(pmin));
                if (nmax > -INFINITY) atomicMax(&negArr[gj], enc(nmax));
            }
        }
    }
}

// ---- kernel 3: per-row loss + mean over valid rows ----
__global__ void tl_final(const unsigned* __restrict__ posArr,
                         const unsigned* __restrict__ negArr,
                         float* __restrict__ out) {
    const int tid = threadIdx.x; // 256 threads
    float sum = 0.0f;
    int   count = 0;
    for (int i = tid; i < NROW; i += 256) {
        const unsigned pe = posArr[i];
        const unsigned ne = negArr[i];
        const bool valid = (pe != POS_INIT) && (ne != NEG_INIT);
        const float dap = sqrtf(fmaxf(2.0f - 2.0f * dec(pe), 0.0f));
        const float dan = sqrtf(fmaxf(2.0f - 2.0f * dec(ne), 0.0f));
        const float per = fmaxf(dap - dan + MARGIN, 0.0f);
        if (valid) { sum += per; count += 1; }
    }
    #pragma unroll
    for (int m = 32; m >= 1; m >>= 1) {
        sum   += __shfl_xor(sum, m);
        count += __shfl_xor(count, m);
    }
    __shared__ float ssum[4];
    __shared__ int   scnt[4];
    const int wave = tid >> 6, lane = tid & 63;
    if (lane == 0) { ssum[wave] = sum; scnt[wave] = count; }
    __syncthreads();
    if (tid == 0) {
        float s = ssum[0] + ssum[1] + ssum[2] + ssum[3];
        int   c = scnt[0] + scnt[1] + scnt[2] + scnt[3];
        out[0] = (c > 0) ? (s / (float)c) : 0.0f;
    }
}

extern "C" void kernel_launch(void* const* d_in, const int* in_sizes, int n_in,
                              void* d_out, int out_size, void* d_ws, size_t ws_size,
                              hipStream_t stream) {
    const float* E      = (const float*)d_in[0];
    const int*   labels = (const int*)d_in[1];
    float*       out    = (float*)d_out;

    char* ws = (char*)d_ws;
    __hip_bfloat16* Ebf   = (__hip_bfloat16*)ws;                       // 4 MB
    unsigned* posArr      = (unsigned*)(ws + (size_t)NROW * DIM * 2);  // 16 KB
    unsigned* negArr      = posArr + NROW;                             // 16 KB

    tl_norm<<<NROW / 4, 256, 0, stream>>>(E, Ebf, posArr, negArr);
    tl_gram<<<NPAIR, 256, 0, stream>>>(Ebf, labels, posArr, negArr);
    tl_final<<<1, 256, 0, stream>>>(posArr, negArr, out);
}